// Round 4
// baseline (1957.697 us; speedup 1.0000x reference)
//
#include <hip/hip_runtime.h>

#define N_ 100000
#define D_ 128
#define O_ 128
#define V_ 3
#define E_ 400000
#define NB_SCAN 98   // ceil(N/1024)

typedef unsigned short u16;

__device__ __forceinline__ float b2f(u16 u) {
    union { float f; unsigned int i; } x; x.i = ((unsigned int)u) << 16; return x.f;
}
__device__ __forceinline__ u16 f2b(float f) {
    union { float f; unsigned int i; } x; x.f = f;
    unsigned int r = x.i + 0x7FFFu + ((x.i >> 16) & 1u);
    return (u16)(r >> 16);
}

template<int F32> __device__ __forceinline__ float LD(const void* p, size_t i) {
    if (F32) return ((const float*)p)[i];
    return b2f(((const u16*)p)[i]);
}
template<int F32> __device__ __forceinline__ float4 LD4(const void* p, size_t i) {
    if (F32) return *(const float4*)((const float*)p + i);
    ushort4 u = *(const ushort4*)((const u16*)p + i);
    return make_float4(b2f(u.x), b2f(u.y), b2f(u.z), b2f(u.w));
}

// ---------------- dtype detector: fp32 vs bf16 element stream ----------------
__global__ void k_detect(const u16* __restrict__ feat, int* __restrict__ flag) {
    if (threadIdx.x == 0 && blockIdx.x == 0) {
        int bad = 0, zeros = 0;
        for (int i = 0; i < 128; ++i) {
            u16 u = feat[2 * i];          // low half of fp32 / even bf16 element
            if (u == 0) zeros++;
            float v = b2f(u);
            if (!(v > -128.f && v < 128.f)) bad++;   // NaN also lands here
        }
        // fp32 stream: low halves are random mantissa bits (bad ~60/128) or
        // exactly zero if values are bf16-rounded fp32 (zeros ~128).
        flag[0] = (bad >= 16 || zeros >= 64) ? 1 : 0;
    }
}

// ---------------- W1 = sl_w @ fus_w[:128] (fp32), b1 = sl_b @ fus_w[:128]+fus_b
template<int F32>
__global__ __launch_bounds__(256) void k_prew(const int* __restrict__ flag,
                                              const void* sl_w, const void* sl_b,
                                              const void* fus_w, const void* fus_b,
                                              float* __restrict__ W1,
                                              float* __restrict__ b1) {
    if (flag[0] != F32) return;
    int gid = blockIdx.x * 256 + threadIdx.x;   // 64 blocks -> 16384 threads
    int d = gid >> 7, o = gid & 127;
    float acc = 0.f;
    for (int k = 0; k < 128; ++k)
        acc += LD<F32>(sl_w, d * 128 + k) * LD<F32>(fus_w, k * 128 + o);
    W1[gid] = acc;
    if (gid < 128) {
        float accb = 0.f;
        for (int k = 0; k < 128; ++k)
            accb += LD<F32>(sl_b, k) * LD<F32>(fus_w, k * 128 + gid);
        b1[gid] = accb + LD<F32>(fus_b, gid);
    }
}

// ---------------- label-aware attention: class_probs + node_att --------------
template<int F32>
__global__ __launch_bounds__(256) void k_att(const int* __restrict__ flag,
                                             const void* feat,
                                             const void* la_w1, const void* la_b1,
                                             const void* la_w2, const void* la_b2,
                                             const void* pred_w, const void* pred_b,
                                             const void* att_bias,
                                             float* __restrict__ natt,
                                             void* d_out) {
    if (flag[0] != F32) return;
    __shared__ float la1f[16384];   // 64KB: la_w1 [2,128,64] as fp32
    __shared__ float predwf[256];
    __shared__ float lab1f[128], law2f[128];
    __shared__ float xrow[512];

    const int tid = threadIdx.x;
    const int nl = tid >> 6, k = tid & 63;       // 4 nodes x 1 wave each
    const int nodebase = blockIdx.x * 4;
    const int node = nodebase + nl;

    for (int i = tid; i < 4096; i += 256)
        ((float4*)la1f)[i] = LD4<F32>(la_w1, (size_t)i * 4);
    predwf[tid] = LD<F32>(pred_w, tid);
    if (tid < 128) { lab1f[tid] = LD<F32>(la_b1, tid); law2f[tid] = LD<F32>(la_w2, tid); }
    if (tid < 128)
        ((float4*)xrow)[tid] = LD4<F32>(feat, (size_t)nodebase * 128 + tid * 4);
    __syncthreads();

    float part0, part1;
    {
        float a0 = 0.f, a1 = 0.f;
        for (int d = 0; d < 128; ++d) {
            float xv = xrow[nl * 128 + d];
            a0 += xv * la1f[d * 64 + k];
            a1 += xv * la1f[8192 + d * 64 + k];
        }
        float h0 = fmaxf(a0 + lab1f[k], 0.f);
        float h1 = fmaxf(a1 + lab1f[64 + k], 0.f);
        part0 = h0 * law2f[k];
        part1 = h1 * law2f[64 + k];
    }
    float x0 = xrow[nl * 128 + k], x1 = xrow[nl * 128 + k + 64];
    float lg0 = x0 * predwf[k * 2 + 0] + x1 * predwf[(k + 64) * 2 + 0];
    float lg1 = x0 * predwf[k * 2 + 1] + x1 * predwf[(k + 64) * 2 + 1];

    for (int s = 32; s >= 1; s >>= 1) {
        part0 += __shfl_xor(part0, s);
        part1 += __shfl_xor(part1, s);
        lg0   += __shfl_xor(lg0, s);
        lg1   += __shfl_xor(lg1, s);
    }
    float l0 = lg0 + LD<F32>(pred_b, 0), l1 = lg1 + LD<F32>(pred_b, 1);
    float m = fmaxf(l0, l1);
    float e0 = __expf(l0 - m), e1 = __expf(l1 - m);
    float inv = 1.f / (e0 + e1);
    float p0 = e0 * inv, p1 = e1 * inv;
    float sc0 = 1.f / (1.f + __expf(-(part0 + LD<F32>(la_b2, 0))));
    float sc1 = 1.f / (1.f + __expf(-(part1 + LD<F32>(la_b2, 1))));
    if (k == 0) {
        natt[node] = sc0 * p0 + sc1 * p1 + LD<F32>(att_bias, 0);
        if (F32) {
            float* pr = (float*)d_out + (size_t)N_ * O_;
            pr[node * 2 + 0] = p0; pr[node * 2 + 1] = p1;
        } else {
            u16* pr = (u16*)d_out + (size_t)N_ * O_;
            pr[node * 2 + 0] = f2b(p0); pr[node * 2 + 1] = f2b(p1);
        }
    }
}

// ---------------- CSR build: count / scan / place ----------------------------
__global__ __launch_bounds__(256) void k_count(const int* __restrict__ ei_dst,
                                               int* __restrict__ counts) {
    int e = blockIdx.x * 256 + threadIdx.x;
    if (e < E_) atomicAdd(&counts[ei_dst[e]], 1);
}

__global__ __launch_bounds__(256) void k_scan_bsum(const int* __restrict__ counts,
                                                   int* __restrict__ bsum) {
    __shared__ int red[256];
    const int b = blockIdx.x, tid = threadIdx.x;
    const int base = b * 1024;
    int s = 0;
    for (int i = tid; i < 1024; i += 256) {
        int idx = base + i;
        s += (idx < N_) ? counts[idx] : 0;
    }
    red[tid] = s;
    __syncthreads();
    for (int st = 128; st >= 1; st >>= 1) {
        if (tid < st) red[tid] += red[tid + st];
        __syncthreads();
    }
    if (tid == 0) bsum[b] = red[0];
}

__global__ void k_scan_spine(int* __restrict__ bsum) {
    if (threadIdx.x == 0 && blockIdx.x == 0) {
        int acc = 0;
        for (int i = 0; i < NB_SCAN; ++i) { int v = bsum[i]; bsum[i] = acc; acc += v; }
    }
}

__global__ __launch_bounds__(256) void k_scan_write(int* __restrict__ counts,
                                                    const int* __restrict__ bsum,
                                                    int* __restrict__ offs) {
    __shared__ int lsum[256];
    const int b = blockIdx.x, tid = threadIdx.x;
    const int base = b * 1024;
    int c[4]; int s = 0;
    #pragma unroll
    for (int k = 0; k < 4; ++k) {
        int idx = base + tid * 4 + k;
        c[k] = (idx < N_) ? counts[idx] : 0;
        s += c[k];
    }
    lsum[tid] = s;
    __syncthreads();
    for (int st = 1; st < 256; st <<= 1) {
        int t = (tid >= st) ? lsum[tid - st] : 0;
        __syncthreads();
        lsum[tid] += t;
        __syncthreads();
    }
    int off = bsum[b] + lsum[tid] - s;
    #pragma unroll
    for (int k = 0; k < 4; ++k) {
        int idx = base + tid * 4 + k;
        if (idx < N_) { offs[idx] = off; counts[idx] = off; }
        off += c[k];
    }
}

__global__ __launch_bounds__(256) void k_place(const int* __restrict__ ei_dst,
                                               int* __restrict__ cursor,
                                               int* __restrict__ perm) {
    int e = blockIdx.x * 256 + threadIdx.x;
    if (e < E_) {
        int pos = atomicAdd(&cursor[ei_dst[e]], 1);
        perm[pos] = e;
    }
    // afterwards cursor[n] == row end
}

// ---------------- fused: 3 views + softmax + fusion + LayerNorm --------------
template<int F32>
__global__ __launch_bounds__(256) void k_fused(const int* __restrict__ flag,
                                               const void* feat,
                                               const int* __restrict__ ei,
                                               const void* ew_all,
                                               const int* __restrict__ offs3,
                                               const int* __restrict__ ends3,
                                               const int* __restrict__ perm3,
                                               const void* rel_w, const void* rel_b,
                                               const void* gate_w, const void* gate_b,
                                               const void* vpref,
                                               const void* va_w1, const void* va_b1,
                                               const void* va_w2, const void* va_b2,
                                               const float* __restrict__ natt,
                                               const float* __restrict__ W1,
                                               const float* __restrict__ b1,
                                               const void* fus_w,
                                               const void* ft_w, const void* ft_b,
                                               const void* ln_g, const void* ln_beta,
                                               void* d_out) {
    if (flag[0] != F32) return;
    __shared__ float wbuf[16384];    // 64KB fp32 weight staging
    __shared__ float xrow[1024];
    __shared__ float zrow[1024];     // gathered z; later reused as aggs (wave-private rows)
    __shared__ float pewt[1024];     // pe in v-loop; wt after (wave-private rows)
    __shared__ float vsc[8][3];

    const int tid = threadIdx.x;
    const int nl = tid >> 5, lane = tid & 31, o4 = lane * 4;
    const int nodebase = blockIdx.x * 8;
    const int node = nodebase + nl;

    if (tid < 256)
        ((float4*)xrow)[tid] = LD4<F32>(feat, (size_t)nodebase * 128 + tid * 4);

    float viewv[3][4];

    #pragma unroll
    for (int v = 0; v < 3; ++v) {
        const int* offs = offs3 + v * N_;
        const int* ends = ends3 + v * N_;
        const int* perm = perm3 + (size_t)v * E_;
        const int* esrc = ei + (size_t)v * 2 * E_;

        for (int i = tid; i < 4096; i += 256)
            ((float4*)wbuf)[i] = LD4<F32>(rel_w, (size_t)v * 16384 + (size_t)i * 4);

        // gather: z = sum_e ew_e * x[src_e], wsn = sum_e ew_e
        float z0 = 0.f, z1 = 0.f, z2 = 0.f, z3 = 0.f, wsn = 0.f;
        {
            const int jend = ends[node];
            for (int j = offs[node]; j < jend; ++j) {
                int e = perm[j];
                float w = LD<F32>(ew_all, (size_t)v * E_ + e);
                int src = esrc[e];
                float4 x4 = LD4<F32>(feat, (size_t)src * 128 + o4);
                z0 += w * x4.x; z1 += w * x4.y;
                z2 += w * x4.z; z3 += w * x4.w;
                wsn += w;
            }
        }
        zrow[nl * 128 + o4 + 0] = z0; zrow[nl * 128 + o4 + 1] = z1;
        zrow[nl * 128 + o4 + 2] = z2; zrow[nl * 128 + o4 + 3] = z3;
        __syncthreads();

        // agg = z @ rel_w + wsn * rel_b   (then store agg back into zrow)
        float acc[4] = {0.f, 0.f, 0.f, 0.f};
        for (int d = 0; d < 128; ++d) {
            float z = zrow[nl * 128 + d];
            float4 w4 = ((const float4*)wbuf)[d * 32 + lane];
            acc[0] += z * w4.x; acc[1] += z * w4.y;
            acc[2] += z * w4.z; acc[3] += z * w4.w;
        }
        #pragma unroll
        for (int i = 0; i < 4; ++i) {
            acc[i] += wsn * LD<F32>(rel_b, v * 128 + o4 + i);
            zrow[nl * 128 + o4 + i] = acc[i];   // zrow now holds agg
        }
        __syncthreads();
        for (int i = tid; i < 4096; i += 256)
            ((float4*)wbuf)[i] = LD4<F32>(gate_w, (size_t)v * 16384 + (size_t)i * 4);
        __syncthreads();

        // gate = sigmoid(agg @ gate_w + gate_b); view = gate*agg (registers)
        float acc2[4] = {0.f, 0.f, 0.f, 0.f};
        for (int kk = 0; kk < 128; ++kk) {
            float a = zrow[nl * 128 + kk];
            float4 w4 = ((const float4*)wbuf)[kk * 32 + lane];
            acc2[0] += a * w4.x; acc2[1] += a * w4.y;
            acc2[2] += a * w4.z; acc2[3] += a * w4.w;
        }
        #pragma unroll
        for (int i = 0; i < 4; ++i) {
            float g = 1.f / (1.f + __expf(-(acc2[i] + LD<F32>(gate_b, v * 128 + o4 + i))));
            viewv[v][i] = g * acc[i];
            pewt[nl * 128 + o4 + i] = viewv[v][i] * LD<F32>(vpref, v * 128 + o4 + i);
        }
        __syncthreads();
        for (int i = tid; i < 2048; i += 256)
            ((float4*)wbuf)[i] = LD4<F32>(va_w1, (size_t)i * 4);
        __syncthreads();

        // vh = relu(pe @ va_w1 + va_b1); vscore = vh . va_w2 + va_b2
        float av0 = 0.f, av1 = 0.f;
        const int k2 = lane * 2;
        for (int j = 0; j < 128; ++j) {
            float p = pewt[nl * 128 + j];
            float2 w2 = ((const float2*)wbuf)[j * 32 + lane];
            av0 += p * w2.x; av1 += p * w2.y;
        }
        float vh0 = fmaxf(av0 + LD<F32>(va_b1, k2), 0.f);
        float vh1 = fmaxf(av1 + LD<F32>(va_b1, k2 + 1), 0.f);
        float part = vh0 * LD<F32>(va_w2, k2) + vh1 * LD<F32>(va_w2, k2 + 1);
        for (int s = 16; s >= 1; s >>= 1) part += __shfl_xor(part, s);
        if (lane == 0) vsc[nl][v] = part + LD<F32>(va_b2, 0);
        __syncthreads();
    }

    // softmax over views * node_att -> weighted combined (into pewt as wt)
    {
        float s0 = vsc[nl][0], s1 = vsc[nl][1], s2 = vsc[nl][2];
        float m = fmaxf(s0, fmaxf(s1, s2));
        float e0 = __expf(s0 - m), e1 = __expf(s1 - m), e2 = __expf(s2 - m);
        float inv = 1.f / (e0 + e1 + e2);
        float na = natt[node];
        float a0 = e0 * inv * na, a1 = e1 * inv * na, a2 = e2 * inv * na;
        #pragma unroll
        for (int i = 0; i < 4; ++i)
            pewt[nl * 128 + o4 + i] = a0 * viewv[0][i] + a1 * viewv[1][i] + a2 * viewv[2][i];
    }
    for (int i = tid; i < 4096; i += 256)
        ((float4*)wbuf)[i] = ((const float4*)W1)[i];
    __syncthreads();

    // accf = X @ W1
    float accf[4] = {0.f, 0.f, 0.f, 0.f};
    for (int d = 0; d < 128; ++d) {
        float xv = xrow[nl * 128 + d];
        float4 w4 = ((const float4*)wbuf)[d * 32 + lane];
        accf[0] += xv * w4.x; accf[1] += xv * w4.y;
        accf[2] += xv * w4.z; accf[3] += xv * w4.w;
    }
    __syncthreads();
    for (int i = tid; i < 4096; i += 256)
        ((float4*)wbuf)[i] = LD4<F32>(fus_w, 16384 + (size_t)i * 4);
    __syncthreads();

    // accf += wt @ fus_w[128:]; f = relu(accf + b1)
    for (int j = 0; j < 128; ++j) {
        float wv = pewt[nl * 128 + j];
        float4 w4 = ((const float4*)wbuf)[j * 32 + lane];
        accf[0] += wv * w4.x; accf[1] += wv * w4.y;
        accf[2] += wv * w4.z; accf[3] += wv * w4.w;
    }
    float f[4];
    #pragma unroll
    for (int i = 0; i < 4; ++i) f[i] = fmaxf(accf[i] + b1[o4 + i], 0.f);
    __syncthreads();
    for (int i = tid; i < 4096; i += 256)
        ((float4*)wbuf)[i] = LD4<F32>(ft_w, (size_t)i * 4);
    __syncthreads();

    // out = f + X @ ft_w + ft_b, then LayerNorm
    float t[4] = {0.f, 0.f, 0.f, 0.f};
    for (int d = 0; d < 128; ++d) {
        float xv = xrow[nl * 128 + d];
        float4 w4 = ((const float4*)wbuf)[d * 32 + lane];
        t[0] += xv * w4.x; t[1] += xv * w4.y;
        t[2] += xv * w4.z; t[3] += xv * w4.w;
    }
    float ov[4];
    float sum = 0.f, ssq = 0.f;
    #pragma unroll
    for (int i = 0; i < 4; ++i) {
        ov[i] = f[i] + t[i] + LD<F32>(ft_b, o4 + i);
        sum += ov[i]; ssq += ov[i] * ov[i];
    }
    for (int s = 16; s >= 1; s >>= 1) { sum += __shfl_xor(sum, s); ssq += __shfl_xor(ssq, s); }
    float mu = sum * (1.f / 128.f);
    float var = ssq * (1.f / 128.f) - mu * mu;
    float rs = rsqrtf(var + 1e-5f);
    float r0 = (ov[0] - mu) * rs * LD<F32>(ln_g, o4 + 0) + LD<F32>(ln_beta, o4 + 0);
    float r1 = (ov[1] - mu) * rs * LD<F32>(ln_g, o4 + 1) + LD<F32>(ln_beta, o4 + 1);
    float r2 = (ov[2] - mu) * rs * LD<F32>(ln_g, o4 + 2) + LD<F32>(ln_beta, o4 + 2);
    float r3 = (ov[3] - mu) * rs * LD<F32>(ln_g, o4 + 3) + LD<F32>(ln_beta, o4 + 3);
    if (F32) {
        *(float4*)((float*)d_out + (size_t)node * 128 + o4) = make_float4(r0, r1, r2, r3);
    } else {
        ushort4 o16; o16.x = f2b(r0); o16.y = f2b(r1); o16.z = f2b(r2); o16.w = f2b(r3);
        *(ushort4*)((u16*)d_out + (size_t)node * 128 + o4) = o16;
    }
}

extern "C" void kernel_launch(void* const* d_in, const int* in_sizes, int n_in,
                              void* d_out, int out_size, void* d_ws, size_t ws_size,
                              hipStream_t stream) {
    const void* feat     = d_in[0];
    const int*  ei       = (const int*)d_in[1];
    const void* ew       = d_in[2];
    const void* rel_w    = d_in[3];
    const void* rel_b    = d_in[4];
    const void* gate_w   = d_in[5];
    const void* gate_b   = d_in[6];
    const void* la_w1    = d_in[7];
    const void* la_b1    = d_in[8];
    const void* la_w2    = d_in[9];
    const void* la_b2    = d_in[10];
    const void* pred_w   = d_in[11];
    const void* pred_b   = d_in[12];
    const void* att_bias = d_in[13];
    const void* view_pref= d_in[14];
    const void* va_w1    = d_in[15];
    const void* va_b1    = d_in[16];
    const void* va_w2    = d_in[17];
    const void* va_b2    = d_in[18];
    const void* ft_w     = d_in[19];
    const void* ft_b     = d_in[20];
    const void* sl_w     = d_in[21];
    const void* sl_b     = d_in[22];
    const void* fus_w    = d_in[23];
    const void* fus_b    = d_in[24];
    const void* ln_g     = d_in[25];
    const void* ln_beta  = d_in[26];

    // workspace layout (~7.7 MB total)
    int*   flag  = (int*)d_ws;                    // 4
    int*   offs3 = flag + 4;                      // 3N
    int*   cur3  = offs3 + 3 * N_;                // 3N
    int*   perm3 = cur3 + 3 * N_;                 // 3E
    int*   bsum  = perm3 + 3 * E_;                // 128
    float* natt  = (float*)(bsum + 128);          // N
    float* W1    = natt + N_;                     // 128*128 fp32
    float* b1    = W1 + D_ * O_;                  // 128

    k_detect<<<1, 64, 0, stream>>>((const u16*)feat, flag);
    k_prew<0><<<64, 256, 0, stream>>>(flag, sl_w, sl_b, fus_w, fus_b, W1, b1);
    k_prew<1><<<64, 256, 0, stream>>>(flag, sl_w, sl_b, fus_w, fus_b, W1, b1);
    k_att<0><<<N_ / 4, 256, 0, stream>>>(flag, feat, la_w1, la_b1, la_w2, la_b2,
                                         pred_w, pred_b, att_bias, natt, d_out);
    k_att<1><<<N_ / 4, 256, 0, stream>>>(flag, feat, la_w1, la_b1, la_w2, la_b2,
                                         pred_w, pred_b, att_bias, natt, d_out);
    hipMemsetAsync(cur3, 0, 3 * N_ * sizeof(int), stream);
    const int egrid = (E_ + 255) / 256;
    for (int v = 0; v < V_; ++v) {
        const int* ei_dst = ei + (size_t)v * 2 * E_ + E_;
        int* cursor = cur3 + v * N_;
        int* offs   = offs3 + v * N_;
        int* perm   = perm3 + (size_t)v * E_;
        k_count<<<egrid, 256, 0, stream>>>(ei_dst, cursor);
        k_scan_bsum<<<NB_SCAN, 256, 0, stream>>>(cursor, bsum);
        k_scan_spine<<<1, 64, 0, stream>>>(bsum);
        k_scan_write<<<NB_SCAN, 256, 0, stream>>>(cursor, bsum, offs);
        k_place<<<egrid, 256, 0, stream>>>(ei_dst, cursor, perm);
    }
    k_fused<0><<<N_ / 8, 256, 0, stream>>>(flag, feat, ei, ew, offs3, cur3, perm3,
                                           rel_w, rel_b, gate_w, gate_b, view_pref,
                                           va_w1, va_b1, va_w2, va_b2,
                                           natt, W1, b1, fus_w, ft_w, ft_b,
                                           ln_g, ln_beta, d_out);
    k_fused<1><<<N_ / 8, 256, 0, stream>>>(flag, feat, ei, ew, offs3, cur3, perm3,
                                           rel_w, rel_b, gate_w, gate_b, view_pref,
                                           va_w1, va_b1, va_w2, va_b2,
                                           natt, W1, b1, fus_w, ft_w, ft_b,
                                           ln_g, ln_beta, d_out);
}

// Round 5
// 1131.064 us; speedup vs baseline: 1.7308x; 1.7308x over previous
//
#include <hip/hip_runtime.h>

#define N_ 100000
#define D_ 128
#define O_ 128
#define V_ 3
#define E_ 400000
#define NB_SCAN 98   // ceil(N/1024)
#define MB 32        // nodes per k_fused block
#define NBLK (N_ / MB)
#define LDA 136      // padded bf16 row stride (16B-aligned, conflict-free frags)

typedef unsigned short u16;
typedef __attribute__((ext_vector_type(8))) short bf16x8;   // 8 bf16 = 4 VGPRs
typedef __attribute__((ext_vector_type(4))) float f32x4;

#define MFMA16x16x32 __builtin_amdgcn_mfma_f32_16x16x32_bf16

__device__ __forceinline__ float b2f(u16 u) {
    union { float f; unsigned int i; } x; x.i = ((unsigned int)u) << 16; return x.f;
}
__device__ __forceinline__ u16 f2b(float f) {
    union { float f; unsigned int i; } x; x.f = f;
    unsigned int r = x.i + 0x7FFFu + ((x.i >> 16) & 1u);
    return (u16)(r >> 16);
}

template<int F32> __device__ __forceinline__ float LD(const void* p, size_t i) {
    if (F32) return ((const float*)p)[i];
    return b2f(((const u16*)p)[i]);
}
template<int F32> __device__ __forceinline__ float4 LD4(const void* p, size_t i) {
    if (F32) return *(const float4*)((const float*)p + i);
    ushort4 u = *(const ushort4*)((const u16*)p + i);
    return make_float4(b2f(u.x), b2f(u.y), b2f(u.z), b2f(u.w));
}

// ---------------- dtype detector: fp32 vs bf16 element stream ----------------
__global__ void k_detect(const u16* __restrict__ feat, int* __restrict__ flag) {
    if (threadIdx.x == 0 && blockIdx.x == 0) {
        int bad = 0, zeros = 0;
        for (int i = 0; i < 128; ++i) {
            u16 u = feat[2 * i];
            if (u == 0) zeros++;
            float v = b2f(u);
            if (!(v > -128.f && v < 128.f)) bad++;
        }
        flag[0] = (bad >= 16 || zeros >= 64) ? 1 : 0;
    }
}

// -------- W1T[o][d] (bf16) = (sl_w @ fus_w[:128])^T ; b1 = sl_b@fus1 + fus_b --
template<int F32>
__global__ __launch_bounds__(256) void k_prew(const int* __restrict__ flag,
                                              const void* sl_w, const void* sl_b,
                                              const void* fus_w, const void* fus_b,
                                              u16* __restrict__ W1T,
                                              float* __restrict__ b1) {
    if (flag[0] != F32) return;
    int gid = blockIdx.x * 256 + threadIdx.x;   // 64 blocks
    int d = gid >> 7, o = gid & 127;
    float acc = 0.f;
    for (int k = 0; k < 128; ++k)
        acc += LD<F32>(sl_w, d * 128 + k) * LD<F32>(fus_w, k * 128 + o);
    W1T[o * 128 + d] = f2b(acc);
    if (gid < 128) {
        float accb = 0.f;
        for (int k = 0; k < 128; ++k)
            accb += LD<F32>(sl_b, k) * LD<F32>(fus_w, k * 128 + gid);
        b1[gid] = accb + LD<F32>(fus_b, gid);
    }
}

// -------- transpose weights to bf16 [n][k] global arrays (L2-resident) -------
template<int F32>
__global__ __launch_bounds__(256) void k_prep(const int* __restrict__ flag,
                                              const void* rel_w, const void* gate_w,
                                              const void* va_w1, const void* fus_w,
                                              const void* ft_w,
                                              u16* __restrict__ relT,
                                              u16* __restrict__ gateT,
                                              u16* __restrict__ vaT,
                                              u16* __restrict__ fus2T,
                                              u16* __restrict__ ftT) {
    if (flag[0] != F32) return;
    int id = blockIdx.x * 256 + threadIdx.x;
    if (id < 49152) {
        int v = id >> 14, r = id & 16383, o = r >> 7, d = r & 127;
        relT[id] = f2b(LD<F32>(rel_w, (size_t)v * 16384 + d * 128 + o));
    } else if (id < 98304) {
        int t = id - 49152, v = t >> 14, r = t & 16383, o = r >> 7, d = r & 127;
        gateT[t] = f2b(LD<F32>(gate_w, (size_t)v * 16384 + d * 128 + o));
    } else if (id < 106496) {
        int t = id - 98304, n = t >> 7, k = t & 127;
        vaT[t] = f2b(LD<F32>(va_w1, k * 64 + n));
    } else if (id < 122880) {
        int t = id - 106496, n = t >> 7, k = t & 127;
        fus2T[t] = f2b(LD<F32>(fus_w, (128 + k) * 128 + n));
    } else if (id < 139264) {
        int t = id - 122880, o = t >> 7, d = t & 127;
        ftT[t] = f2b(LD<F32>(ft_w, d * 128 + o));
    }
}

// ---------------- label-aware attention: class_probs + node_att --------------
template<int F32>
__global__ __launch_bounds__(256) void k_att(const int* __restrict__ flag,
                                             const void* feat,
                                             const void* la_w1, const void* la_b1,
                                             const void* la_w2, const void* la_b2,
                                             const void* pred_w, const void* pred_b,
                                             const void* att_bias,
                                             float* __restrict__ natt,
                                             void* d_out) {
    if (flag[0] != F32) return;
    __shared__ float la1f[16384];
    __shared__ float predwf[256];
    __shared__ float lab1f[128], law2f[128];
    __shared__ float xrow[512];

    const int tid = threadIdx.x;
    const int nl = tid >> 6, k = tid & 63;
    const int nodebase = blockIdx.x * 4;
    const int node = nodebase + nl;

    for (int i = tid; i < 4096; i += 256)
        ((float4*)la1f)[i] = LD4<F32>(la_w1, (size_t)i * 4);
    predwf[tid] = LD<F32>(pred_w, tid);
    if (tid < 128) { lab1f[tid] = LD<F32>(la_b1, tid); law2f[tid] = LD<F32>(la_w2, tid); }
    if (tid < 128)
        ((float4*)xrow)[tid] = LD4<F32>(feat, (size_t)nodebase * 128 + tid * 4);
    __syncthreads();

    float part0, part1;
    {
        float a0 = 0.f, a1 = 0.f;
        for (int d = 0; d < 128; ++d) {
            float xv = xrow[nl * 128 + d];
            a0 += xv * la1f[d * 64 + k];
            a1 += xv * la1f[8192 + d * 64 + k];
        }
        float h0 = fmaxf(a0 + lab1f[k], 0.f);
        float h1 = fmaxf(a1 + lab1f[64 + k], 0.f);
        part0 = h0 * law2f[k];
        part1 = h1 * law2f[64 + k];
    }
    float x0 = xrow[nl * 128 + k], x1 = xrow[nl * 128 + k + 64];
    float lg0 = x0 * predwf[k * 2 + 0] + x1 * predwf[(k + 64) * 2 + 0];
    float lg1 = x0 * predwf[k * 2 + 1] + x1 * predwf[(k + 64) * 2 + 1];

    for (int s = 32; s >= 1; s >>= 1) {
        part0 += __shfl_xor(part0, s);
        part1 += __shfl_xor(part1, s);
        lg0   += __shfl_xor(lg0, s);
        lg1   += __shfl_xor(lg1, s);
    }
    float l0 = lg0 + LD<F32>(pred_b, 0), l1 = lg1 + LD<F32>(pred_b, 1);
    float m = fmaxf(l0, l1);
    float e0 = __expf(l0 - m), e1 = __expf(l1 - m);
    float inv = 1.f / (e0 + e1);
    float p0 = e0 * inv, p1 = e1 * inv;
    float sc0 = 1.f / (1.f + __expf(-(part0 + LD<F32>(la_b2, 0))));
    float sc1 = 1.f / (1.f + __expf(-(part1 + LD<F32>(la_b2, 1))));
    if (k == 0) {
        natt[node] = sc0 * p0 + sc1 * p1 + LD<F32>(att_bias, 0);
        if (F32) {
            float* pr = (float*)d_out + (size_t)N_ * O_;
            pr[node * 2 + 0] = p0; pr[node * 2 + 1] = p1;
        } else {
            u16* pr = (u16*)d_out + (size_t)N_ * O_;
            pr[node * 2 + 0] = f2b(p0); pr[node * 2 + 1] = f2b(p1);
        }
    }
}

// ---------------- CSR build: count / scan / place ----------------------------
__global__ __launch_bounds__(256) void k_count(const int* __restrict__ ei_dst,
                                               int* __restrict__ counts) {
    int e = blockIdx.x * 256 + threadIdx.x;
    if (e < E_) atomicAdd(&counts[ei_dst[e]], 1);
}

__global__ __launch_bounds__(256) void k_scan_bsum(const int* __restrict__ counts,
                                                   int* __restrict__ bsum) {
    __shared__ int red[256];
    const int b = blockIdx.x, tid = threadIdx.x;
    const int base = b * 1024;
    int s = 0;
    for (int i = tid; i < 1024; i += 256) {
        int idx = base + i;
        s += (idx < N_) ? counts[idx] : 0;
    }
    red[tid] = s;
    __syncthreads();
    for (int st = 128; st >= 1; st >>= 1) {
        if (tid < st) red[tid] += red[tid + st];
        __syncthreads();
    }
    if (tid == 0) bsum[b] = red[0];
}

__global__ void k_scan_spine(int* __restrict__ bsum) {
    if (threadIdx.x == 0 && blockIdx.x == 0) {
        int acc = 0;
        for (int i = 0; i < NB_SCAN; ++i) { int v = bsum[i]; bsum[i] = acc; acc += v; }
    }
}

__global__ __launch_bounds__(256) void k_scan_write(int* __restrict__ counts,
                                                    const int* __restrict__ bsum,
                                                    int* __restrict__ offs) {
    __shared__ int lsum[256];
    const int b = blockIdx.x, tid = threadIdx.x;
    const int base = b * 1024;
    int c[4]; int s = 0;
    #pragma unroll
    for (int k = 0; k < 4; ++k) {
        int idx = base + tid * 4 + k;
        c[k] = (idx < N_) ? counts[idx] : 0;
        s += c[k];
    }
    lsum[tid] = s;
    __syncthreads();
    for (int st = 1; st < 256; st <<= 1) {
        int t = (tid >= st) ? lsum[tid - st] : 0;
        __syncthreads();
        lsum[tid] += t;
        __syncthreads();
    }
    int off = bsum[b] + lsum[tid] - s;
    #pragma unroll
    for (int k = 0; k < 4; ++k) {
        int idx = base + tid * 4 + k;
        if (idx < N_) { offs[idx] = off; counts[idx] = off; }
        off += c[k];
    }
}

__global__ __launch_bounds__(256) void k_place(const int* __restrict__ ei_dst,
                                               int* __restrict__ cursor,
                                               int* __restrict__ perm) {
    int e = blockIdx.x * 256 + threadIdx.x;
    if (e < E_) {
        int pos = atomicAdd(&cursor[ei_dst[e]], 1);
        perm[pos] = e;
    }
}

// ---------------- fused MFMA pipeline: 3 views + combine + fusion + LN -------
template<int F32>
__global__ __launch_bounds__(256, 2) void k_fused(const int* __restrict__ flag,
        const void* feat, const int* __restrict__ ei, const void* ew_all,
        const int* __restrict__ offs3, const int* __restrict__ ends3,
        const int* __restrict__ perm3,
        const u16* __restrict__ relT, const u16* __restrict__ gateT,
        const u16* __restrict__ vaT, const u16* __restrict__ W1T,
        const u16* __restrict__ fus2T, const u16* __restrict__ ftT,
        const void* rel_b, const void* gate_b, const void* vpref,
        const void* va_b1, const void* va_w2, const void* va_b2,
        const float* __restrict__ natt, const float* __restrict__ b1,
        const void* ft_b, const void* ln_g, const void* ln_beta,
        void* d_out) {
    if (flag[0] != F32) return;

    __shared__ __align__(16) u16 Wt[128 * LDA];   // 34816 B, also reused as out staging
    __shared__ __align__(16) u16 xA[MB * LDA];    // features, bf16 A-layout
    __shared__ __align__(16) u16 Ab[MB * LDA];    // rotating activation A buffer
    __shared__ float wsn_s[MB];
    __shared__ float vsc_s[MB][3];
    __shared__ float red_s[4][MB][2];
    __shared__ float mrs_s[MB][2];
    __shared__ float aw_s[MB][3];
    __shared__ float relb_s[128], gateb_s[128], vp_s[128];
    __shared__ float vab1_s[64], vaw2_s[64];
    __shared__ float b1_s[128], ftb_s[128], lng_s[128], lnb_s[128];

    const int tid = threadIdx.x;
    const int wid = tid >> 6;
    const int L = tid & 63, q = L >> 4, i = L & 15;
    const int nb = wid * 32;
    const int nodebase = blockIdx.x * MB;
    const int nl = tid >> 5, l32 = tid & 31, o4 = l32 * 4;
    const f32x4 zz = {0.f, 0.f, 0.f, 0.f};

    auto stageW = [&](const u16* src) {
        for (int idx = tid; idx < 2048; idx += 256) {
            int o = idx >> 4, s = idx & 15;
            *(uint4*)&Wt[o * LDA + s * 8] = *(const uint4*)&src[o * 128 + s * 8];
        }
    };
    auto stageW64 = [&](const u16* src) {
        for (int idx = tid; idx < 1024; idx += 256) {
            int o = idx >> 4, s = idx & 15;
            *(uint4*)&Wt[o * LDA + s * 8] = *(const uint4*)&src[o * 128 + s * 8];
        }
    };
    auto gather = [&](int v) {
        const int* offs = offs3 + v * N_;
        const int* ends = ends3 + v * N_;
        const int* perm = perm3 + (size_t)v * E_;
        const int* esrc = ei + (size_t)v * 2 * E_;
        #pragma unroll
        for (int rep = 0; rep < 4; ++rep) {
            int m = rep * 8 + nl;
            int node = nodebase + m;
            float z0 = 0.f, z1 = 0.f, z2 = 0.f, z3 = 0.f, wsn = 0.f;
            int jend = ends[node];
            for (int j = offs[node]; j < jend; ++j) {
                int e = perm[j];
                float w = LD<F32>(ew_all, (size_t)v * E_ + e);
                int src = esrc[e];
                float4 x4 = LD4<F32>(feat, (size_t)src * 128 + o4);
                z0 += w * x4.x; z1 += w * x4.y; z2 += w * x4.z; z3 += w * x4.w;
                wsn += w;
            }
            uint2 u;
            u.x = (unsigned)f2b(z0) | ((unsigned)f2b(z1) << 16);
            u.y = (unsigned)f2b(z2) | ((unsigned)f2b(z3) << 16);
            *(uint2*)&Ab[m * LDA + o4] = u;
            if (l32 == 0) wsn_s[m] = wsn;
        }
    };
    auto ldf = [&](const u16* B, int row, int k0) -> bf16x8 {
        return *(const bf16x8*)&B[row * LDA + k0];
    };
    auto gemm128 = [&](const u16* A, f32x4 acc[2][2]) {
        #pragma unroll
        for (int kk = 0; kk < 4; ++kk) {
            int k0 = q * 8 + kk * 32;
            bf16x8 a0 = ldf(A, i, k0);
            bf16x8 a1 = ldf(A, i + 16, k0);
            bf16x8 bb0 = ldf(Wt, nb + i, k0);
            bf16x8 bb1 = ldf(Wt, nb + 16 + i, k0);
            acc[0][0] = MFMA16x16x32(a0, bb0, acc[0][0], 0, 0, 0);
            acc[0][1] = MFMA16x16x32(a0, bb1, acc[0][1], 0, 0, 0);
            acc[1][0] = MFMA16x16x32(a1, bb0, acc[1][0], 0, 0, 0);
            acc[1][1] = MFMA16x16x32(a1, bb1, acc[1][1], 0, 0, 0);
        }
    };

    // ---- phase 0: stage xA (bf16), small vectors, Wt<-relT[0], gather v0 ----
    for (int idx = tid; idx < MB * 16; idx += 256) {
        int m = idx >> 4, s = idx & 15;
        float4 f0 = LD4<F32>(feat, (size_t)(nodebase + m) * 128 + s * 8);
        float4 f1 = LD4<F32>(feat, (size_t)(nodebase + m) * 128 + s * 8 + 4);
        uint4 u;
        u.x = (unsigned)f2b(f0.x) | ((unsigned)f2b(f0.y) << 16);
        u.y = (unsigned)f2b(f0.z) | ((unsigned)f2b(f0.w) << 16);
        u.z = (unsigned)f2b(f1.x) | ((unsigned)f2b(f1.y) << 16);
        u.w = (unsigned)f2b(f1.z) | ((unsigned)f2b(f1.w) << 16);
        *(uint4*)&xA[m * LDA + s * 8] = u;
    }
    if (tid < 64) { vab1_s[tid] = LD<F32>(va_b1, tid); vaw2_s[tid] = LD<F32>(va_w2, tid); }
    if (tid < 128) {
        b1_s[tid] = b1[tid];
        ftb_s[tid] = LD<F32>(ft_b, tid);
        lng_s[tid] = LD<F32>(ln_g, tid);
        lnb_s[tid] = LD<F32>(ln_beta, tid);
        relb_s[tid] = LD<F32>(rel_b, tid);
    }
    stageW(relT);
    gather(0);
    __syncthreads();

    f32x4 viewr[3][2][2];

    #pragma unroll
    for (int v = 0; v < 3; ++v) {
        // ---- agg = z @ rel_w + wsn*rel_b ----
        f32x4 accA[2][2] = {{zz, zz}, {zz, zz}};
        gemm128(Ab, accA);
        __syncthreads();
        #pragma unroll
        for (int mt = 0; mt < 2; ++mt)
            #pragma unroll
            for (int nt = 0; nt < 2; ++nt)
                #pragma unroll
                for (int r = 0; r < 4; ++r) {
                    int row = mt * 16 + q * 4 + r, col = nb + nt * 16 + i;
                    float a = accA[mt][nt][r] + wsn_s[row] * relb_s[col];
                    accA[mt][nt][r] = a;
                    Ab[row * LDA + col] = f2b(a);
                }
        stageW(gateT + (size_t)v * 16384);
        if (tid < 128) { gateb_s[tid] = LD<F32>(gate_b, v * 128 + tid);
                         vp_s[tid] = LD<F32>(vpref, v * 128 + tid); }
        __syncthreads();

        // ---- gate = sigmoid(agg @ gate_w + gb); view = gate*agg; pe -> Ab ----
        f32x4 acc2[2][2] = {{zz, zz}, {zz, zz}};
        gemm128(Ab, acc2);
        __syncthreads();
        #pragma unroll
        for (int mt = 0; mt < 2; ++mt)
            #pragma unroll
            for (int nt = 0; nt < 2; ++nt)
                #pragma unroll
                for (int r = 0; r < 4; ++r) {
                    int row = mt * 16 + q * 4 + r, col = nb + nt * 16 + i;
                    float g = 1.f / (1.f + __expf(-(acc2[mt][nt][r] + gateb_s[col])));
                    float vv = g * accA[mt][nt][r];
                    viewr[v][mt][nt][r] = vv;
                    Ab[row * LDA + col] = f2b(vv * vp_s[col]);
                }
        stageW64(vaT);
        __syncthreads();

        // ---- vh = relu(pe @ va_w1 + b); vscore = vh . va_w2 + b2 ----
        f32x4 accV[2] = {zz, zz};
        const int nbv = wid * 16, colv = nbv + i;
        #pragma unroll
        for (int kk = 0; kk < 4; ++kk) {
            int k0 = q * 8 + kk * 32;
            bf16x8 a0 = ldf(Ab, i, k0);
            bf16x8 a1 = ldf(Ab, i + 16, k0);
            bf16x8 bb = ldf(Wt, nbv + i, k0);
            accV[0] = MFMA16x16x32(a0, bb, accV[0], 0, 0, 0);
            accV[1] = MFMA16x16x32(a1, bb, accV[1], 0, 0, 0);
        }
        float part[2][4];
        #pragma unroll
        for (int mt = 0; mt < 2; ++mt)
            #pragma unroll
            for (int r = 0; r < 4; ++r) {
                float vh = fmaxf(accV[mt][r] + vab1_s[colv], 0.f);
                part[mt][r] = vh * vaw2_s[colv];
            }
        #pragma unroll
        for (int s = 1; s <= 8; s <<= 1)
            #pragma unroll
            for (int mt = 0; mt < 2; ++mt)
                #pragma unroll
                for (int r = 0; r < 4; ++r)
                    part[mt][r] += __shfl_xor(part[mt][r], s);
        if (i == 0)
            #pragma unroll
            for (int mt = 0; mt < 2; ++mt)
                #pragma unroll
                for (int r = 0; r < 4; ++r)
                    red_s[wid][mt * 16 + q * 4 + r][0] = part[mt][r];
        __syncthreads();
        if (tid < MB)
            vsc_s[tid][v] = red_s[0][tid][0] + red_s[1][tid][0] +
                            red_s[2][tid][0] + red_s[3][tid][0] + LD<F32>(va_b2, 0);
        if (v < 2) {
            stageW(relT + (size_t)(v + 1) * 16384);
            if (tid < 128) relb_s[tid] = LD<F32>(rel_b, (v + 1) * 128 + tid);
            gather(v + 1);
        }
        __syncthreads();
    }

    // ---- combine: softmax over views * natt -> wt (Ab); stage W1T ----
    if (tid < MB) {
        float s0 = vsc_s[tid][0], s1 = vsc_s[tid][1], s2 = vsc_s[tid][2];
        float mx = fmaxf(s0, fmaxf(s1, s2));
        float e0 = __expf(s0 - mx), e1 = __expf(s1 - mx), e2 = __expf(s2 - mx);
        float inv = natt[nodebase + tid] / (e0 + e1 + e2);
        aw_s[tid][0] = e0 * inv; aw_s[tid][1] = e1 * inv; aw_s[tid][2] = e2 * inv;
    }
    stageW(W1T);
    __syncthreads();

    // wt -> Ab, and accF = X @ W1 (reads xA, Wt only)
    #pragma unroll
    for (int mt = 0; mt < 2; ++mt)
        #pragma unroll
        for (int nt = 0; nt < 2; ++nt)
            #pragma unroll
            for (int r = 0; r < 4; ++r) {
                int row = mt * 16 + q * 4 + r, col = nb + nt * 16 + i;
                float wv = aw_s[row][0] * viewr[0][mt][nt][r] +
                           aw_s[row][1] * viewr[1][mt][nt][r] +
                           aw_s[row][2] * viewr[2][mt][nt][r];
                Ab[row * LDA + col] = f2b(wv);
            }
    f32x4 accF[2][2] = {{zz, zz}, {zz, zz}};
    gemm128(xA, accF);
    __syncthreads();
    stageW(fus2T);
    __syncthreads();
    gemm128(Ab, accF);     // accF += wt @ fus_w[128:]
    __syncthreads();
    stageW(ftT);
    float fR[2][2][4];
    #pragma unroll
    for (int mt = 0; mt < 2; ++mt)
        #pragma unroll
        for (int nt = 0; nt < 2; ++nt)
            #pragma unroll
            for (int r = 0; r < 4; ++r) {
                int col = nb + nt * 16 + i;
                fR[mt][nt][r] = fmaxf(accF[mt][nt][r] + b1_s[col], 0.f);
            }
    __syncthreads();
    f32x4 accT[2][2] = {{zz, zz}, {zz, zz}};
    gemm128(xA, accT);

    // ---- out = f + X@ft_w + ft_b, LayerNorm ----
    float ov[2][2][4], ps[2][4], pq[2][4];
    #pragma unroll
    for (int mt = 0; mt < 2; ++mt)
        #pragma unroll
        for (int r = 0; r < 4; ++r) { ps[mt][r] = 0.f; pq[mt][r] = 0.f; }
    #pragma unroll
    for (int mt = 0; mt < 2; ++mt)
        #pragma unroll
        for (int nt = 0; nt < 2; ++nt)
            #pragma unroll
            for (int r = 0; r < 4; ++r) {
                int col = nb + nt * 16 + i;
                float o = fR[mt][nt][r] + accT[mt][nt][r] + ftb_s[col];
                ov[mt][nt][r] = o;
                ps[mt][r] += o; pq[mt][r] += o * o;
            }
    #pragma unroll
    for (int s = 1; s <= 8; s <<= 1)
        #pragma unroll
        for (int mt = 0; mt < 2; ++mt)
            #pragma unroll
            for (int r = 0; r < 4; ++r) {
                ps[mt][r] += __shfl_xor(ps[mt][r], s);
                pq[mt][r] += __shfl_xor(pq[mt][r], s);
            }
    if (i == 0)
        #pragma unroll
        for (int mt = 0; mt < 2; ++mt)
            #pragma unroll
            for (int r = 0; r < 4; ++r) {
                red_s[wid][mt * 16 + q * 4 + r][0] = ps[mt][r];
                red_s[wid][mt * 16 + q * 4 + r][1] = pq[mt][r];
            }
    __syncthreads();
    if (tid < MB) {
        float sm = red_s[0][tid][0] + red_s[1][tid][0] + red_s[2][tid][0] + red_s[3][tid][0];
        float sq = red_s[0][tid][1] + red_s[1][tid][1] + red_s[2][tid][1] + red_s[3][tid][1];
        float mu = sm * (1.f / 128.f);
        float var = sq * (1.f / 128.f) - mu * mu;
        mrs_s[tid][0] = mu; mrs_s[tid][1] = rsqrtf(var + 1e-5f);
    }
    __syncthreads();
    #pragma unroll
    for (int mt = 0; mt < 2; ++mt)
        #pragma unroll
        for (int nt = 0; nt < 2; ++nt)
            #pragma unroll
            for (int r = 0; r < 4; ++r) {
                int row = mt * 16 + q * 4 + r, col = nb + nt * 16 + i;
                float val = (ov[mt][nt][r] - mrs_s[row][0]) * mrs_s[row][1]
                            * lng_s[col] + lnb_s[col];
                if (F32) ((float*)Wt)[row * 128 + col] = val;
                else     ((u16*)Wt)[row * 128 + col] = f2b(val);
            }
    __syncthreads();
    if (F32) {
        float* op = (float*)d_out + (size_t)nodebase * 128;
        for (int idx = tid; idx < 1024; idx += 256)
            ((float4*)op)[idx] = ((float4*)Wt)[idx];
    } else {
        u16* op = (u16*)d_out + (size_t)nodebase * 128;
        for (int idx = tid; idx < 512; idx += 256)
            ((uint4*)op)[idx] = ((uint4*)Wt)[idx];
    }
}

extern "C" void kernel_launch(void* const* d_in, const int* in_sizes, int n_in,
                              void* d_out, int out_size, void* d_ws, size_t ws_size,
                              hipStream_t stream) {
    const void* feat     = d_in[0];
    const int*  ei       = (const int*)d_in[1];
    const void* ew       = d_in[2];
    const void* rel_w    = d_in[3];
    const void* rel_b    = d_in[4];
    const void* gate_w   = d_in[5];
    const void* gate_b   = d_in[6];
    const void* la_w1    = d_in[7];
    const void* la_b1    = d_in[8];
    const void* la_w2    = d_in[9];
    const void* la_b2    = d_in[10];
    const void* pred_w   = d_in[11];
    const void* pred_b   = d_in[12];
    const void* att_bias = d_in[13];
    const void* view_pref= d_in[14];
    const void* va_w1    = d_in[15];
    const void* va_b1    = d_in[16];
    const void* va_w2    = d_in[17];
    const void* va_b2    = d_in[18];
    const void* ft_w     = d_in[19];
    const void* ft_b     = d_in[20];
    const void* sl_w     = d_in[21];
    const void* sl_b     = d_in[22];
    const void* fus_w    = d_in[23];
    const void* fus_b    = d_in[24];
    const void* ln_g     = d_in[25];
    const void* ln_beta  = d_in[26];

    // workspace layout (~8.0 MB total)
    int*   flag  = (int*)d_ws;                    // 4
    int*   offs3 = flag + 4;                      // 3N
    int*   cur3  = offs3 + 3 * N_;                // 3N
    int*   perm3 = cur3 + 3 * N_;                 // 3E
    int*   bsum  = perm3 + 3 * E_;                // 128
    float* natt  = (float*)(bsum + 128);          // N
    float* b1    = natt + N_;                     // 128
    u16*   W1T   = (u16*)(b1 + 128);              // 16384
    u16*   relT  = W1T + 16384;                   // 3*16384
    u16*   gateT = relT + 3 * 16384;              // 3*16384
    u16*   vaT   = gateT + 3 * 16384;             // 8192
    u16*   fus2T = vaT + 8192;                    // 16384
    u16*   ftT   = fus2T + 16384;                 // 16384

    k_detect<<<1, 64, 0, stream>>>((const u16*)feat, flag);
    k_prew<0><<<64, 256, 0, stream>>>(flag, sl_w, sl_b, fus_w, fus_b, W1T, b1);
    k_prew<1><<<64, 256, 0, stream>>>(flag, sl_w, sl_b, fus_w, fus_b, W1T, b1);
    k_prep<0><<<544, 256, 0, stream>>>(flag, rel_w, gate_w, va_w1, fus_w, ft_w,
                                       relT, gateT, vaT, fus2T, ftT);
    k_prep<1><<<544, 256, 0, stream>>>(flag, rel_w, gate_w, va_w1, fus_w, ft_w,
                                       relT, gateT, vaT, fus2T, ftT);
    k_att<0><<<N_ / 4, 256, 0, stream>>>(flag, feat, la_w1, la_b1, la_w2, la_b2,
                                         pred_w, pred_b, att_bias, natt, d_out);
    k_att<1><<<N_ / 4, 256, 0, stream>>>(flag, feat, la_w1, la_b1, la_w2, la_b2,
                                         pred_w, pred_b, att_bias, natt, d_out);
    hipMemsetAsync(cur3, 0, 3 * N_ * sizeof(int), stream);
    const int egrid = (E_ + 255) / 256;
    for (int v = 0; v < V_; ++v) {
        const int* ei_dst = ei + (size_t)v * 2 * E_ + E_;
        int* cursor = cur3 + v * N_;
        int* offs   = offs3 + v * N_;
        int* perm   = perm3 + (size_t)v * E_;
        k_count<<<egrid, 256, 0, stream>>>(ei_dst, cursor);
        k_scan_bsum<<<NB_SCAN, 256, 0, stream>>>(cursor, bsum);
        k_scan_spine<<<1, 64, 0, stream>>>(bsum);
        k_scan_write<<<NB_SCAN, 256, 0, stream>>>(cursor, bsum, offs);
        k_place<<<egrid, 256, 0, stream>>>(ei_dst, cursor, perm);
    }
    k_fused<0><<<NBLK, 256, 0, stream>>>(flag, feat, ei, ew, offs3, cur3, perm3,
                                         relT, gateT, vaT, W1T, fus2T, ftT,
                                         rel_b, gate_b, view_pref,
                                         va_b1, va_w2, va_b2, natt, b1,
                                         ft_b, ln_g, ln_beta, d_out);
    k_fused<1><<<NBLK, 256, 0, stream>>>(flag, feat, ei, ew, offs3, cur3, perm3,
                                         relT, gateT, vaT, W1T, fus2T, ftT,
                                         rel_b, gate_b, view_pref,
                                         va_b1, va_w2, va_b2, natt, b1,
                                         ft_b, ln_g, ln_beta, d_out);
}

// Round 7
// 697.998 us; speedup vs baseline: 2.8047x; 1.6204x over previous
//
#include <hip/hip_runtime.h>

#define N_ 100000
#define D_ 128
#define O_ 128
#define V_ 3
#define E_ 400000
#define NB_SCAN 98   // ceil(N/1024)
#define EGRID 1563   // ceil(E/256)
#define MB 32        // nodes per k_fused block
#define NBLK (N_ / MB)
#define LDA 136      // padded bf16 row stride (16B-aligned, conflict-light frags)

typedef unsigned short u16;
typedef __attribute__((ext_vector_type(8))) short bf16x8;   // 8 bf16 = 4 VGPRs
typedef __attribute__((ext_vector_type(4))) float f32x4;

#define MFMA16x16x32 __builtin_amdgcn_mfma_f32_16x16x32_bf16

__device__ __forceinline__ float b2f(u16 u) {
    union { float f; unsigned int i; } x; x.i = ((unsigned int)u) << 16; return x.f;
}
__device__ __forceinline__ u16 f2b(float f) {
    union { float f; unsigned int i; } x; x.f = f;
    unsigned int r = x.i + 0x7FFFu + ((x.i >> 16) & 1u);
    return (u16)(r >> 16);
}

template<int F32> __device__ __forceinline__ float LD(const void* p, size_t i) {
    if (F32) return ((const float*)p)[i];
    return b2f(((const u16*)p)[i]);
}
template<int F32> __device__ __forceinline__ float4 LD4(const void* p, size_t i) {
    if (F32) return *(const float4*)((const float*)p + i);
    ushort4 u = *(const ushort4*)((const u16*)p + i);
    return make_float4(b2f(u.x), b2f(u.y), b2f(u.z), b2f(u.w));
}

// ---------------- dtype detector: fp32 vs bf16 element stream ----------------
__global__ void k_detect(const u16* __restrict__ feat, int* __restrict__ flag) {
    if (threadIdx.x == 0 && blockIdx.x == 0) {
        int bad = 0, zeros = 0;
        for (int i = 0; i < 128; ++i) {
            u16 u = feat[2 * i];
            if (u == 0) zeros++;
            float v = b2f(u);
            if (!(v > -128.f && v < 128.f)) bad++;
        }
        flag[0] = (bad >= 16 || zeros >= 64) ? 1 : 0;
    }
}

// -------- W1T[o][d] (bf16) = (sl_w @ fus_w[:128])^T ; b1 = sl_b@fus1 + fus_b --
template<int F32>
__global__ __launch_bounds__(256) void k_prew(const int* __restrict__ flag,
                                              const void* sl_w, const void* sl_b,
                                              const void* fus_w, const void* fus_b,
                                              u16* __restrict__ W1T,
                                              float* __restrict__ b1) {
    if (flag[0] != F32) return;
    int gid = blockIdx.x * 256 + threadIdx.x;   // 64 blocks
    int d = gid >> 7, o = gid & 127;
    float acc = 0.f;
    for (int k = 0; k < 128; ++k)
        acc += LD<F32>(sl_w, d * 128 + k) * LD<F32>(fus_w, k * 128 + o);
    W1T[o * 128 + d] = f2b(acc);
    if (gid < 128) {
        float accb = 0.f;
        for (int k = 0; k < 128; ++k)
            accb += LD<F32>(sl_b, k) * LD<F32>(fus_w, k * 128 + gid);
        b1[gid] = accb + LD<F32>(fus_b, gid);
    }
}

// -------- transpose weights to bf16 [n][k] global arrays (L2-resident) -------
template<int F32>
__global__ __launch_bounds__(256) void k_prep(const int* __restrict__ flag,
                                              const void* rel_w, const void* gate_w,
                                              const void* va_w1, const void* fus_w,
                                              const void* ft_w, const void* la_w1,
                                              u16* __restrict__ relT,
                                              u16* __restrict__ gateT,
                                              u16* __restrict__ vaT,
                                              u16* __restrict__ fus2T,
                                              u16* __restrict__ ftT,
                                              u16* __restrict__ laT) {
    if (flag[0] != F32) return;
    int id = blockIdx.x * 256 + threadIdx.x;
    if (id < 49152) {
        int v = id >> 14, r = id & 16383, o = r >> 7, d = r & 127;
        relT[id] = f2b(LD<F32>(rel_w, (size_t)v * 16384 + d * 128 + o));
    } else if (id < 98304) {
        int t = id - 49152, v = t >> 14, r = t & 16383, o = r >> 7, d = r & 127;
        gateT[t] = f2b(LD<F32>(gate_w, (size_t)v * 16384 + d * 128 + o));
    } else if (id < 106496) {
        int t = id - 98304, n = t >> 7, k = t & 127;
        vaT[t] = f2b(LD<F32>(va_w1, k * 64 + n));
    } else if (id < 122880) {
        int t = id - 106496, n = t >> 7, k = t & 127;
        fus2T[t] = f2b(LD<F32>(fus_w, (128 + k) * 128 + n));
    } else if (id < 139264) {
        int t = id - 122880, o = t >> 7, d = t & 127;
        ftT[t] = f2b(LD<F32>(ft_w, d * 128 + o));
    } else if (id < 155648) {
        int t = id - 139264, n = t >> 7, d = t & 127;
        int c = n >> 6, j = n & 63;
        laT[t] = f2b(LD<F32>(la_w1, c * 8192 + d * 64 + j));
    }
}

// ---------------- CSR build: count / scan / place (all 3 views per launch) ---
__global__ __launch_bounds__(256) void k_count(const int* __restrict__ ei,
                                               int* __restrict__ cur3) {
    int v = blockIdx.x / EGRID;
    int e = (blockIdx.x % EGRID) * 256 + threadIdx.x;
    if (e < E_) atomicAdd(&cur3[v * N_ + ei[(size_t)v * 2 * E_ + E_ + e]], 1);
}

__global__ __launch_bounds__(256) void k_scan_bsum(const int* __restrict__ cur3,
                                                   int* __restrict__ bsum) {
    __shared__ int red[256];
    const int v = blockIdx.x / NB_SCAN, b = blockIdx.x % NB_SCAN, tid = threadIdx.x;
    const int base = b * 1024;
    const int* counts = cur3 + v * N_;
    int s = 0;
    for (int i = tid; i < 1024; i += 256) {
        int idx = base + i;
        s += (idx < N_) ? counts[idx] : 0;
    }
    red[tid] = s;
    __syncthreads();
    for (int st = 128; st >= 1; st >>= 1) {
        if (tid < st) red[tid] += red[tid + st];
        __syncthreads();
    }
    if (tid == 0) bsum[v * 128 + b] = red[0];
}

__global__ void k_scan_spine(int* __restrict__ bsum) {
    if (threadIdx.x == 0 && blockIdx.x == 0) {
        for (int v = 0; v < 3; ++v) {
            int acc = 0;
            for (int i = 0; i < NB_SCAN; ++i) {
                int t = bsum[v * 128 + i]; bsum[v * 128 + i] = acc; acc += t;
            }
        }
    }
}

__global__ __launch_bounds__(256) void k_scan_write(int* __restrict__ cur3,
                                                    const int* __restrict__ bsum,
                                                    int* __restrict__ offs3) {
    __shared__ int lsum[256];
    const int v = blockIdx.x / NB_SCAN, b = blockIdx.x % NB_SCAN, tid = threadIdx.x;
    const int base = b * 1024;
    int* counts = cur3 + v * N_;
    int* offs   = offs3 + v * N_;
    int c[4]; int s = 0;
    #pragma unroll
    for (int k = 0; k < 4; ++k) {
        int idx = base + tid * 4 + k;
        c[k] = (idx < N_) ? counts[idx] : 0;
        s += c[k];
    }
    lsum[tid] = s;
    __syncthreads();
    for (int st = 1; st < 256; st <<= 1) {
        int t = (tid >= st) ? lsum[tid - st] : 0;
        __syncthreads();
        lsum[tid] += t;
        __syncthreads();
    }
    int off = bsum[v * 128 + b] + lsum[tid] - s;
    #pragma unroll
    for (int k = 0; k < 4; ++k) {
        int idx = base + tid * 4 + k;
        if (idx < N_) { offs[idx] = off; counts[idx] = off; }
        off += c[k];
    }
}

// place: srcw[pos] = {src, weight-bits} — single-indirection CSR values
template<int F32>
__global__ __launch_bounds__(256) void k_place(const int* __restrict__ flag,
                                               const int* __restrict__ ei,
                                               const void* ew_all,
                                               int* __restrict__ cur3,
                                               int2* __restrict__ srcw3) {
    if (flag[0] != F32) return;
    int v = blockIdx.x / EGRID;
    int e = (blockIdx.x % EGRID) * 256 + threadIdx.x;
    if (e < E_) {
        int dst = ei[(size_t)v * 2 * E_ + E_ + e];
        int src = ei[(size_t)v * 2 * E_ + e];
        float w = LD<F32>(ew_all, (size_t)v * E_ + e);
        int pos = atomicAdd(&cur3[v * N_ + dst], 1);
        int2 sw; sw.x = src; sw.y = __float_as_int(w);
        srcw3[(size_t)v * E_ + pos] = sw;
    }
    // afterwards cur3[v*N+n] == row end
}

// ------ fused MFMA pipeline: label-att + 3 views + combine + fusion + LN -----
template<int F32>
__global__ __launch_bounds__(256, 2) void k_fused(const int* __restrict__ flag,
        const void* feat, const int2* __restrict__ srcw3,
        const int* __restrict__ offs3, const int* __restrict__ ends3,
        const u16* __restrict__ relT, const u16* __restrict__ gateT,
        const u16* __restrict__ vaT, const u16* __restrict__ W1T,
        const u16* __restrict__ fus2T, const u16* __restrict__ ftT,
        const u16* __restrict__ laT,
        const void* rel_b, const void* gate_b, const void* vpref,
        const void* va_b1, const void* va_w2, const void* va_b2,
        const void* la_b1, const void* la_w2, const void* la_b2,
        const void* pred_w, const void* pred_b, const void* att_bias,
        const float* __restrict__ b1,
        const void* ft_b, const void* ln_g, const void* ln_beta,
        void* d_out) {
    if (flag[0] != F32) return;

    __shared__ __align__(16) u16 Wt[128 * LDA];   // weight staging; reused as out staging
    __shared__ __align__(16) u16 xA[MB * LDA];    // features, bf16 A-layout
    __shared__ __align__(16) u16 Ab[MB * LDA];    // rotating activation A buffer
    __shared__ float wsn_s[MB];
    __shared__ float vsc_s[MB][3];
    __shared__ float red_s[4][MB][2];
    __shared__ float mrs_s[MB][2];
    __shared__ float aw_s[MB][3];
    __shared__ float natt_s[MB];
    __shared__ float lg_s[MB][2];
    __shared__ float relb_s[128], gateb_s[128], vp_s[128];
    __shared__ float vab1_s[64], vaw2_s[64];
    __shared__ float lab1_s[128], law2_s[128], predw_s[256];
    __shared__ float b1_s[128], ftb_s[128], lng_s[128], lnb_s[128];

    const int tid = threadIdx.x;
    const int wid = tid >> 6;
    const int L = tid & 63, q = L >> 4, i = L & 15;
    const int nb = wid * 32;
    const int nodebase = blockIdx.x * MB;
    const int nl = tid >> 5, l32 = tid & 31, o4 = l32 * 4;
    const f32x4 zz = {0.f, 0.f, 0.f, 0.f};

    auto stageW = [&](const u16* src) {
        for (int idx = tid; idx < 2048; idx += 256) {
            int o = idx >> 4, s = idx & 15;
            *(uint4*)&Wt[o * LDA + s * 8] = *(const uint4*)&src[o * 128 + s * 8];
        }
    };
    auto stageW64 = [&](const u16* src) {
        for (int idx = tid; idx < 1024; idx += 256) {
            int o = idx >> 4, s = idx & 15;
            *(uint4*)&Wt[o * LDA + s * 8] = *(const uint4*)&src[o * 128 + s * 8];
        }
    };
    auto gather = [&](int v) {
        const int* offs = offs3 + v * N_;
        const int* ends = ends3 + v * N_;
        const int2* srcw = srcw3 + (size_t)v * E_;
        #pragma unroll
        for (int rep = 0; rep < 4; ++rep) {
            int m = rep * 8 + nl;
            int node = nodebase + m;
            float z0 = 0.f, z1 = 0.f, z2 = 0.f, z3 = 0.f;
            float y0 = 0.f, y1 = 0.f, y2 = 0.f, y3 = 0.f;
            float wa_s = 0.f, wb_s = 0.f;
            int j = offs[node], jend = ends[node];
            for (; j + 1 < jend; j += 2) {
                int2 a = srcw[j], b = srcw[j + 1];
                float wa = __int_as_float(a.y), wb = __int_as_float(b.y);
                float4 xa = LD4<F32>(feat, (size_t)a.x * 128 + o4);
                float4 xb = LD4<F32>(feat, (size_t)b.x * 128 + o4);
                z0 += wa * xa.x; z1 += wa * xa.y; z2 += wa * xa.z; z3 += wa * xa.w;
                y0 += wb * xb.x; y1 += wb * xb.y; y2 += wb * xb.z; y3 += wb * xb.w;
                wa_s += wa; wb_s += wb;
            }
            if (j < jend) {
                int2 a = srcw[j];
                float wa = __int_as_float(a.y);
                float4 xa = LD4<F32>(feat, (size_t)a.x * 128 + o4);
                z0 += wa * xa.x; z1 += wa * xa.y; z2 += wa * xa.z; z3 += wa * xa.w;
                wa_s += wa;
            }
            z0 += y0; z1 += y1; z2 += y2; z3 += y3;
            uint2 u;
            u.x = (unsigned)f2b(z0) | ((unsigned)f2b(z1) << 16);
            u.y = (unsigned)f2b(z2) | ((unsigned)f2b(z3) << 16);
            *(uint2*)&Ab[m * LDA + o4] = u;
            if (l32 == 0) wsn_s[m] = wa_s + wb_s;
        }
    };
    auto ldf = [&](const u16* B, int row, int k0) -> bf16x8 {
        return *(const bf16x8*)&B[row * LDA + k0];
    };
    auto gemm128 = [&](const u16* A, f32x4 acc[2][2]) {
        #pragma unroll
        for (int kk = 0; kk < 4; ++kk) {
            int k0 = q * 8 + kk * 32;
            bf16x8 a0 = ldf(A, i, k0);
            bf16x8 a1 = ldf(A, i + 16, k0);
            bf16x8 bb0 = ldf(Wt, nb + i, k0);
            bf16x8 bb1 = ldf(Wt, nb + 16 + i, k0);
            acc[0][0] = MFMA16x16x32(a0, bb0, acc[0][0], 0, 0, 0);
            acc[0][1] = MFMA16x16x32(a0, bb1, acc[0][1], 0, 0, 0);
            acc[1][0] = MFMA16x16x32(a1, bb0, acc[1][0], 0, 0, 0);
            acc[1][1] = MFMA16x16x32(a1, bb1, acc[1][1], 0, 0, 0);
        }
    };

    // ---- phase 0: stage xA, consts, Wt<-laT, gather v0 ----
    for (int idx = tid; idx < MB * 16; idx += 256) {
        int m = idx >> 4, s = idx & 15;
        float4 f0 = LD4<F32>(feat, (size_t)(nodebase + m) * 128 + s * 8);
        float4 f1 = LD4<F32>(feat, (size_t)(nodebase + m) * 128 + s * 8 + 4);
        uint4 u;
        u.x = (unsigned)f2b(f0.x) | ((unsigned)f2b(f0.y) << 16);
        u.y = (unsigned)f2b(f0.z) | ((unsigned)f2b(f0.w) << 16);
        u.z = (unsigned)f2b(f1.x) | ((unsigned)f2b(f1.y) << 16);
        u.w = (unsigned)f2b(f1.z) | ((unsigned)f2b(f1.w) << 16);
        *(uint4*)&xA[m * LDA + s * 8] = u;
    }
    if (tid < 64) { vab1_s[tid] = LD<F32>(va_b1, tid); vaw2_s[tid] = LD<F32>(va_w2, tid); }
    if (tid < 128) {
        b1_s[tid] = b1[tid];
        ftb_s[tid] = LD<F32>(ft_b, tid);
        lng_s[tid] = LD<F32>(ln_g, tid);
        lnb_s[tid] = LD<F32>(ln_beta, tid);
        relb_s[tid] = LD<F32>(rel_b, tid);
        lab1_s[tid] = LD<F32>(la_b1, tid);
        law2_s[tid] = LD<F32>(la_w2, tid);
    }
    predw_s[tid] = LD<F32>(pred_w, tid);
    stageW(laT);
    gather(0);
    __syncthreads();

    // ---- label-aware attention: h=relu(X@la1+b1); scores; logits; natt ----
    f32x4 accL[2][2] = {{zz, zz}, {zz, zz}};
    gemm128(xA, accL);
    // logits (128 -> 2) off xA, per 32-lane group
    #pragma unroll
    for (int rep = 0; rep < 4; ++rep) {
        int m = rep * 8 + nl;
        float lg0 = 0.f, lg1 = 0.f;
        #pragma unroll
        for (int t = 0; t < 4; ++t) {
            float xv = b2f(xA[m * LDA + o4 + t]);
            lg0 += xv * predw_s[(o4 + t) * 2 + 0];
            lg1 += xv * predw_s[(o4 + t) * 2 + 1];
        }
        #pragma unroll
        for (int s = 1; s <= 16; s <<= 1) {
            lg0 += __shfl_xor(lg0, s);
            lg1 += __shfl_xor(lg1, s);
        }
        if (l32 == 0) { lg_s[m][0] = lg0; lg_s[m][1] = lg1; }
    }
    __syncthreads();               // everyone done with Wt(laT) + lg_s written
    stageW(relT);
    {
        float partL[2][4];
        #pragma unroll
        for (int mt = 0; mt < 2; ++mt)
            #pragma unroll
            for (int r = 0; r < 4; ++r) {
                float h0 = fmaxf(accL[mt][0][r] + lab1_s[nb + i], 0.f);
                float h1 = fmaxf(accL[mt][1][r] + lab1_s[nb + 16 + i], 0.f);
                partL[mt][r] = h0 * law2_s[nb + i] + h1 * law2_s[nb + 16 + i];
            }
        #pragma unroll
        for (int s = 1; s <= 8; s <<= 1)
            #pragma unroll
            for (int mt = 0; mt < 2; ++mt)
                #pragma unroll
                for (int r = 0; r < 4; ++r)
                    partL[mt][r] += __shfl_xor(partL[mt][r], s);
        if (i == 0)
            #pragma unroll
            for (int mt = 0; mt < 2; ++mt)
                #pragma unroll
                for (int r = 0; r < 4; ++r)
                    red_s[wid][mt * 16 + q * 4 + r][0] = partL[mt][r];
    }
    __syncthreads();               // red_s visible; Wt(relT) staged
    if (tid < MB) {
        float c0 = red_s[0][tid][0] + red_s[1][tid][0] + LD<F32>(la_b2, 0);
        float c1 = red_s[2][tid][0] + red_s[3][tid][0] + LD<F32>(la_b2, 1);
        float s0 = 1.f / (1.f + __expf(-c0));
        float s1 = 1.f / (1.f + __expf(-c1));
        float l0 = lg_s[tid][0] + LD<F32>(pred_b, 0);
        float l1 = lg_s[tid][1] + LD<F32>(pred_b, 1);
        float mx = fmaxf(l0, l1);
        float e0 = __expf(l0 - mx), e1 = __expf(l1 - mx);
        float inv = 1.f / (e0 + e1);
        float p0 = e0 * inv, p1 = e1 * inv;
        natt_s[tid] = s0 * p0 + s1 * p1 + LD<F32>(att_bias, 0);
        int node = nodebase + tid;
        if (F32) {
            float* pr = (float*)d_out + (size_t)N_ * O_;
            pr[node * 2 + 0] = p0; pr[node * 2 + 1] = p1;
        } else {
            u16* pr = (u16*)d_out + (size_t)N_ * O_;
            pr[node * 2 + 0] = f2b(p0); pr[node * 2 + 1] = f2b(p1);
        }
    }
    __syncthreads();

    f32x4 viewr[3][2][2];

    #pragma unroll
    for (int v = 0; v < 3; ++v) {
        // ---- agg = z @ rel_w + wsn*rel_b ----
        f32x4 accA[2][2] = {{zz, zz}, {zz, zz}};
        gemm128(Ab, accA);
        __syncthreads();
        #pragma unroll
        for (int mt = 0; mt < 2; ++mt)
            #pragma unroll
            for (int nt = 0; nt < 2; ++nt)
                #pragma unroll
                for (int r = 0; r < 4; ++r) {
                    int row = mt * 16 + q * 4 + r, col = nb + nt * 16 + i;
                    float a = accA[mt][nt][r] + wsn_s[row] * relb_s[col];
                    accA[mt][nt][r] = a;
                    Ab[row * LDA + col] = f2b(a);
                }
        stageW(gateT + (size_t)v * 16384);
        if (tid < 128) { gateb_s[tid] = LD<F32>(gate_b, v * 128 + tid);
                         vp_s[tid] = LD<F32>(vpref, v * 128 + tid); }
        __syncthreads();

        // ---- gate = sigmoid(agg @ gate_w + gb); view = gate*agg; pe -> Ab ----
        f32x4 acc2[2][2] = {{zz, zz}, {zz, zz}};
        gemm128(Ab, acc2);
        __syncthreads();
        #pragma unroll
        for (int mt = 0; mt < 2; ++mt)
            #pragma unroll
            for (int nt = 0; nt < 2; ++nt)
                #pragma unroll
                for (int r = 0; r < 4; ++r) {
                    int row = mt * 16 + q * 4 + r, col = nb + nt * 16 + i;
                    float g = 1.f / (1.f + __expf(-(acc2[mt][nt][r] + gateb_s[col])));
                    float vv = g * accA[mt][nt][r];
                    viewr[v][mt][nt][r] = vv;
                    Ab[row * LDA + col] = f2b(vv * vp_s[col]);
                }
        stageW64(vaT);
        __syncthreads();

        // ---- vh = relu(pe @ va_w1 + b); vscore = vh . va_w2 + b2 ----
        f32x4 accV[2] = {zz, zz};
        const int nbv = wid * 16, colv = nbv + i;
        #pragma unroll
        for (int kk = 0; kk < 4; ++kk) {
            int k0 = q * 8 + kk * 32;
            bf16x8 a0 = ldf(Ab, i, k0);
            bf16x8 a1 = ldf(Ab, i + 16, k0);
            bf16x8 bb = ldf(Wt, nbv + i, k0);
            accV[0] = MFMA16x16x32(a0, bb, accV[0], 0, 0, 0);
            accV[1] = MFMA16x16x32(a1, bb, accV[1], 0, 0, 0);
        }
        float part[2][4];
        #pragma unroll
        for (int mt = 0; mt < 2; ++mt)
            #pragma unroll
            for (int r = 0; r < 4; ++r) {
                float vh = fmaxf(accV[mt][r] + vab1_s[colv], 0.f);
                part[mt][r] = vh * vaw2_s[colv];
            }
        #pragma unroll
        for (int s = 1; s <= 8; s <<= 1)
            #pragma unroll
            for (int mt = 0; mt < 2; ++mt)
                #pragma unroll
                for (int r = 0; r < 4; ++r)
                    part[mt][r] += __shfl_xor(part[mt][r], s);
        if (i == 0)
            #pragma unroll
            for (int mt = 0; mt < 2; ++mt)
                #pragma unroll
                for (int r = 0; r < 4; ++r)
                    red_s[wid][mt * 16 + q * 4 + r][0] = part[mt][r];
        __syncthreads();
        if (tid < MB)
            vsc_s[tid][v] = red_s[0][tid][0] + red_s[1][tid][0] +
                            red_s[2][tid][0] + red_s[3][tid][0] + LD<F32>(va_b2, 0);
        if (v < 2) {
            stageW(relT + (size_t)(v + 1) * 16384);
            if (tid < 128) relb_s[tid] = LD<F32>(rel_b, (v + 1) * 128 + tid);
            gather(v + 1);
        }
        __syncthreads();
    }

    // ---- combine: softmax over views * natt -> wt (Ab); stage W1T ----
    if (tid < MB) {
        float s0 = vsc_s[tid][0], s1 = vsc_s[tid][1], s2 = vsc_s[tid][2];
        float mx = fmaxf(s0, fmaxf(s1, s2));
        float e0 = __expf(s0 - mx), e1 = __expf(s1 - mx), e2 = __expf(s2 - mx);
        float inv = natt_s[tid] / (e0 + e1 + e2);
        aw_s[tid][0] = e0 * inv; aw_s[tid][1] = e1 * inv; aw_s[tid][2] = e2 * inv;
    }
    stageW(W1T);
    __syncthreads();

    // wt -> Ab, and accF = X @ W1 (reads xA, Wt only)
    #pragma unroll
    for (int mt = 0; mt < 2; ++mt)
        #pragma unroll
        for (int nt = 0; nt < 2; ++nt)
            #pragma unroll
            for (int r = 0; r < 4; ++r) {
                int row = mt * 16 + q * 4 + r, col = nb + nt * 16 + i;
                float wv = aw_s[row][0] * viewr[0][mt][nt][r] +
                           aw_s[row][1] * viewr[1][mt][nt][r] +
                           aw_s[row][2] * viewr[2][mt][nt][r];
                Ab[row * LDA + col] = f2b(wv);
            }
    f32x4 accF[2][2] = {{zz, zz}, {zz, zz}};
    gemm128(xA, accF);
    __syncthreads();
    stageW(fus2T);
    __syncthreads();
    gemm128(Ab, accF);     // accF += wt @ fus_w[128:]
    __syncthreads();
    stageW(ftT);
    float fR[2][2][4];
    #pragma unroll
    for (int mt = 0; mt < 2; ++mt)
        #pragma unroll
        for (int nt = 0; nt < 2; ++nt)
            #pragma unroll
            for (int r = 0; r < 4; ++r) {
                int col = nb + nt * 16 + i;
                fR[mt][nt][r] = fmaxf(accF[mt][nt][r] + b1_s[col], 0.f);
            }
    __syncthreads();
    f32x4 accT[2][2] = {{zz, zz}, {zz, zz}};
    gemm128(xA, accT);

    // ---- out = f + X@ft_w + ft_b, LayerNorm ----
    float ov[2][2][4], ps[2][4], pq[2][4];
    #pragma unroll
    for (int mt = 0; mt < 2; ++mt)
        #pragma unroll
        for (int r = 0; r < 4; ++r) { ps[mt][r] = 0.f; pq[mt][r] = 0.f; }
    #pragma unroll
    for (int mt = 0; mt < 2; ++mt)
        #pragma unroll
        for (int nt = 0; nt < 2; ++nt)
            #pragma unroll
            for (int r = 0; r < 4; ++r) {
                int col = nb + nt * 16 + i;
                float o = fR[mt][nt][r] + accT[mt][nt][r] + ftb_s[col];
                ov[mt][nt][r] = o;
                ps[mt][r] += o; pq[mt][r] += o * o;
            }
    #pragma unroll
    for (int s = 1; s <= 8; s <<= 1)
        #pragma unroll
        for (int mt = 0; mt < 2; ++mt)
            #pragma unroll
            for (int r = 0; r < 4; ++r) {
                ps[mt][r] += __shfl_xor(ps[mt][r], s);
                pq[mt][r] += __shfl_xor(pq[mt][r], s);
            }
    if (i == 0)
        #pragma unroll
        for (int mt = 0; mt < 2; ++mt)
            #pragma unroll
            for (int r = 0; r < 4; ++r) {
                red_s[wid][mt * 16 + q * 4 + r][0] = ps[mt][r];
                red_s[wid][mt * 16 + q * 4 + r][1] = pq[mt][r];
            }
    __syncthreads();
    if (tid < MB) {
        float sm = red_s[0][tid][0] + red_s[1][tid][0] + red_s[2][tid][0] + red_s[3][tid][0];
        float sq = red_s[0][tid][1] + red_s[1][tid][1] + red_s[2][tid][1] + red_s[3][tid][1];
        float mu = sm * (1.f / 128.f);
        float var = sq * (1.f / 128.f) - mu * mu;
        mrs_s[tid][0] = mu; mrs_s[tid][1] = rsqrtf(var + 1e-5f);
    }
    __syncthreads();
    #pragma unroll
    for (int mt = 0; mt < 2; ++mt)
        #pragma unroll
        for (int nt = 0; nt < 2; ++nt)
            #pragma unroll
            for (int r = 0; r < 4; ++r) {
                int row = mt * 16 + q * 4 + r, col = nb + nt * 16 + i;
                float val = (ov[mt][nt][r] - mrs_s[row][0]) * mrs_s[row][1]
                            * lng_s[col] + lnb_s[col];
                if (F32) ((float*)Wt)[row * 128 + col] = val;
                else     ((u16*)Wt)[row * 128 + col] = f2b(val);
            }
    __syncthreads();
    if (F32) {
        float* op = (float*)d_out + (size_t)nodebase * 128;
        for (int idx = tid; idx < 1024; idx += 256)
            ((float4*)op)[idx] = ((float4*)Wt)[idx];
    } else {
        u16* op = (u16*)d_out + (size_t)nodebase * 128;
        for (int idx = tid; idx < 512; idx += 256)
            ((uint4*)op)[idx] = ((uint4*)Wt)[idx];
    }
}

extern "C" void kernel_launch(void* const* d_in, const int* in_sizes, int n_in,
                              void* d_out, int out_size, void* d_ws, size_t ws_size,
                              hipStream_t stream) {
    const void* feat     = d_in[0];
    const int*  ei       = (const int*)d_in[1];
    const void* ew       = d_in[2];
    const void* rel_w    = d_in[3];
    const void* rel_b    = d_in[4];
    const void* gate_w   = d_in[5];
    const void* gate_b   = d_in[6];
    const void* la_w1    = d_in[7];
    const void* la_b1    = d_in[8];
    const void* la_w2    = d_in[9];
    const void* la_b2    = d_in[10];
    const void* pred_w   = d_in[11];
    const void* pred_b   = d_in[12];
    const void* att_bias = d_in[13];
    const void* view_pref= d_in[14];
    const void* va_w1    = d_in[15];
    const void* va_b1    = d_in[16];
    const void* va_w2    = d_in[17];
    const void* va_b2    = d_in[18];
    const void* ft_w     = d_in[19];
    const void* ft_b     = d_in[20];
    const void* sl_w     = d_in[21];
    const void* sl_b     = d_in[22];
    const void* fus_w    = d_in[23];
    const void* fus_b    = d_in[24];
    const void* ln_g     = d_in[25];
    const void* ln_beta  = d_in[26];

    // workspace layout (~12.5 MB total)
    int*   flag  = (int*)d_ws;                    // 4 ints
    int*   offs3 = flag + 4;                      // 3N
    int*   cur3  = offs3 + 3 * N_;                // 3N
    int2*  srcw3 = (int2*)(cur3 + 3 * N_);        // 3E int2 (16B-aligned)
    int*   bsum  = (int*)(srcw3 + 3 * E_);        // 3*128
    float* b1    = (float*)(bsum + 3 * 128);      // 128
    u16*   W1T   = (u16*)(b1 + 128);              // 16384
    u16*   relT  = W1T + 16384;                   // 3*16384
    u16*   gateT = relT + 3 * 16384;              // 3*16384
    u16*   vaT   = gateT + 3 * 16384;             // 8192
    u16*   fus2T = vaT + 8192;                    // 16384
    u16*   ftT   = fus2T + 16384;                 // 16384
    u16*   laT   = ftT + 16384;                   // 16384

    k_detect<<<1, 64, 0, stream>>>((const u16*)feat, flag);
    k_prew<0><<<64, 256, 0, stream>>>(flag, sl_w, sl_b, fus_w, fus_b, W1T, b1);
    k_prew<1><<<64, 256, 0, stream>>>(flag, sl_w, sl_b, fus_w, fus_b, W1T, b1);
    k_prep<0><<<608, 256, 0, stream>>>(flag, rel_w, gate_w, va_w1, fus_w, ft_w, la_w1,
                                       relT, gateT, vaT, fus2T, ftT, laT);
    k_prep<1><<<608, 256, 0, stream>>>(flag, rel_w, gate_w, va_w1, fus_w, ft_w, la_w1,
                                       relT, gateT, vaT, fus2T, ftT, laT);
    (void)hipMemsetAsync(cur3, 0, 3 * N_ * sizeof(int), stream);
    k_count<<<3 * EGRID, 256, 0, stream>>>(ei, cur3);
    k_scan_bsum<<<3 * NB_SCAN, 256, 0, stream>>>(cur3, bsum);
    k_scan_spine<<<1, 64, 0, stream>>>(bsum);
    k_scan_write<<<3 * NB_SCAN, 256, 0, stream>>>(cur3, bsum, offs3);
    k_place<0><<<3 * EGRID, 256, 0, stream>>>(flag, ei, ew, cur3, srcw3);
    k_place<1><<<3 * EGRID, 256, 0, stream>>>(flag, ei, ew, cur3, srcw3);
    k_fused<0><<<NBLK, 256, 0, stream>>>(flag, feat, srcw3, offs3, cur3,
                                         relT, gateT, vaT, W1T, fus2T, ftT, laT,
                                         rel_b, gate_b, view_pref,
                                         va_b1, va_w2, va_b2,
                                         la_b1, la_w2, la_b2, pred_w, pred_b, att_bias,
                                         b1, ft_b, ln_g, ln_beta, d_out);
    k_fused<1><<<NBLK, 256, 0, stream>>>(flag, feat, srcw3, offs3, cur3,
                                         relT, gateT, vaT, W1T, fus2T, ftT, laT,
                                         rel_b, gate_b, view_pref,
                                         va_b1, va_w2, va_b2,
                                         la_b1, la_w2, la_b2, pred_w, pred_b, att_bias,
                                         b1, ft_b, ln_g, ln_beta, d_out);
}